// Round 5
// baseline (1920.763 us; speedup 1.0000x reference)
//
#include <hip/hip_runtime.h>
#include <math.h>

// Problem: S=4096, D=512, H=8, KVH=4, DH=64, M=64, K=8 (B=1)
// STRATEGY: emulate numpy-float32 arithmetic bit-for-bit on the selection-
// critical path (np reference is f32; exact arithmetic flips top-k sites).
//  - np @ (OpenBLAS sgemm): sequential f32 fmaf chain over k, KC=384 split
//  - np .sum(axis=strided): sequential f32 adds in order
//  - np einsum: sequential f32 mul+add (NOT fma), contracted dim innermost
//  - trig/pow tables: correctly-rounded f32 (via f64 then round)
//  - softmax: exact *0.125, fl32(exp64), numpy pairwise-8 sum tree, f32 div

// Workspace (floats)
static constexpr size_t OFF_QKV = 0;              // 4096*1024
static constexpr size_t OFF_Q   = 4194304;        // 8*4096*64   q[h][s][d]
static constexpr size_t OFF_K   = 6291456;        // 4*4096*64   k[kvh][s][d]
static constexpr size_t OFF_V   = 7340032;        // 4*4096*64   v[kvh][s][d]
static constexpr size_t OFF_COS = 8388608;        // 4096*32
static constexpr size_t OFF_SIN = 8519680;        // 4096*32
static constexpr size_t OFF_K1  = 8650752;        // 4*64*32     k1[kvh][r][d]
static constexpr size_t OFF_K2  = 8658944;        // 4*64*32     k2[kvh][c][d]
static constexpr size_t OFF_O   = 8667136;        // 4096*512
static constexpr size_t OFF_W   = 10764288;       // 1024*512

// f32 tables matching numpy: pf=fl32(10000^(dp/32)); invf=fl32(1/pf);
// argf=fl32(s*invf); cs/sn=fl32(cos/sin_64(argf))
__global__ __launch_bounds__(256) void freq_table_kernel(float* __restrict__ cosT,
    float* __restrict__ sinT) {
  int idx = blockIdx.x * 256 + threadIdx.x;   // 0..131071
  int s = idx >> 5;
  int dp = idx & 31;
  double e = (double)dp * (1.0 / 32.0);       // exact dyadic
  float pf = (float)pow(10000.0, e);          // == correctly-rounded powf
  float invf = 1.0f / pf;                     // IEEE f32 divide
  float argf = __fmul_rn((float)s, invf);
  cosT[idx] = (float)cos((double)argf);
  sinT[idx] = (float)sin((double)argf);
}

// QKV gemm emulating OpenBLAS sgemm: per output element, sequential f32 fmaf
// chain in k-order, split at KC=384 (panel boundary adds with plain f32 add).
// C[s][n] = x[s]·wcat[n],  4 outputs per thread.
__global__ __launch_bounds__(256) void qkv_gemm_np(const float* __restrict__ A,
    const float* __restrict__ B, float* __restrict__ C) {
  int t = blockIdx.x * 256 + threadIdx.x;     // 0..1048575
  int s = t >> 8;
  int n0 = (t & 255) << 2;
  const float* a = A + (size_t)s * 512;
  #pragma unroll
  for (int u = 0; u < 4; ++u) {
    const float* b = B + (size_t)(n0 + u) * 512;
    float acc1 = 0.f, acc2 = 0.f;
    for (int k = 0; k < 384; ++k)  acc1 = fmaf(a[k], b[k], acc1);
    for (int k = 384; k < 512; ++k) acc2 = fmaf(a[k], b[k], acc2);
    C[(size_t)s * 1024 + n0 + u] = __fadd_rn(acc1, acc2);
  }
}

// Output gemm (value path, rounding harmless): same structure, no split.
__global__ __launch_bounds__(256) void out_gemm(const float* __restrict__ A,
    const float* __restrict__ B, float* __restrict__ C) {
  int t = blockIdx.x * 256 + threadIdx.x;     // 0..524287
  int s = t >> 7;
  int n0 = (t & 127) << 2;
  const float* a = A + (size_t)s * 512;
  #pragma unroll
  for (int u = 0; u < 4; ++u) {
    const float* b = B + (size_t)(n0 + u) * 512;
    float acc = 0.f;
    for (int k = 0; k < 512; ++k) acc = fmaf(a[k], b[k], acc);
    C[(size_t)s * 512 + n0 + u] = acc;
  }
}

// qkv[s][n] -> rope'd q[h][s][d], k[kvh][s][d]; raw v[kvh][s][d]
// out = fl32( fl32(x*cos) + fl32(rot*sin) )   (numpy two-temp rounding)
__global__ __launch_bounds__(256) void rope_reshape_kernel(const float* __restrict__ raw,
    const float* __restrict__ cosT, const float* __restrict__ sinT,
    float* __restrict__ qb, float* __restrict__ kb, float* __restrict__ vb) {
  int idx = blockIdx.x * 256 + threadIdx.x;
  int s = idx >> 10;
  int n = idx & 1023;
  float val = raw[idx];
  int d = n & 63;
  if (n < 768) {
    int dp = d & 31;
    float cs = cosT[(s << 5) + dp];
    float sn = sinT[(s << 5) + dp];
    int npart = (n - d) + ((d < 32) ? d + 32 : d - 32);
    float partner = raw[(s << 10) + npart];
    float rot = (d < 32) ? -partner : partner;
    float out = __fadd_rn(__fmul_rn(val, cs), __fmul_rn(rot, sn));
    if (n < 512) {
      int h = n >> 6;
      qb[((size_t)(h * 4096 + s) << 6) + d] = out;
    } else {
      int kvh = (n - 512) >> 6;
      kb[((size_t)(kvh * 4096 + s) << 6) + d] = out;
    }
  } else {
    int kvh = (n - 768) >> 6;
    vb[((size_t)(kvh * 4096 + s) << 6) + d] = val;
  }
}

// numpy strided-axis sum: sequential f32 adds in axis order.
// k1[kvh][r][d] = sum_c k[kvh][r*64+c][d]      (d 0..31)
// k2[kvh][c][d] = sum_r k[kvh][r*64+c][d+32]
__global__ __launch_bounds__(256) void k12_np_kernel(const float* __restrict__ kb,
    float* __restrict__ k1t, float* __restrict__ k2t) {
  int id = blockIdx.x * 256 + threadIdx.x;    // 0..16383
  int which = id >> 13;
  int rem = id & 8191;
  int kvh = rem >> 11;
  int rem2 = rem & 2047;
  int i = rem2 >> 5;                          // 0..63
  int d = rem2 & 31;
  const float* base = kb + ((size_t)(kvh * 4096) << 6);
  if (which == 0) {
    float acc = base[((size_t)(i * 64) << 6) + d];
    for (int c = 1; c < 64; ++c)
      acc = __fadd_rn(acc, base[((size_t)(i * 64 + c) << 6) + d]);
    k1t[(kvh * 64 + i) * 32 + d] = acc;
  } else {
    float acc = base[((size_t)i << 6) + d + 32];
    for (int r = 1; r < 64; ++r)
      acc = __fadd_rn(acc, base[((size_t)(r * 64 + i) << 6) + d + 32]);
    k2t[(kvh * 64 + i) * 32 + d] = acc;
  }
}

// One thread per (h,s); all selection arithmetic numpy-f32-faithful.
__global__ __launch_bounds__(256) void attn_np_kernel(const float* __restrict__ qb,
    const float* __restrict__ vb, const float* __restrict__ k1t,
    const float* __restrict__ k2t, float* __restrict__ ob) {
  __shared__ float lk1[2048];   // [r][d] 64x32 for this block's kvh
  __shared__ float lk2[2048];
  int id = blockIdx.x * 256 + threadIdx.x;    // 0..32767
  int h = id >> 12;
  int s = id & 4095;
  int kvh = h >> 1;
  // cooperative LDS load (whole block shares h => same kvh)
  for (int j = threadIdx.x; j < 2048; j += 256) {
    lk1[j] = k1t[kvh * 2048 + j];
    lk2[j] = k2t[kvh * 2048 + j];
  }
  __syncthreads();

  float q[64];
  const float* qp = qb + ((size_t)(h * 4096 + s) << 6);
  for (int d = 0; d < 64; ++d) q[d] = qp[d];

  // stage-1 scores: sgemm-style fmaf chain over d (K=32, no panel split)
  float sc[64];
  float t1v[8], t2v[8];
  int t1i[8], t2i[8];
  for (int r = 0; r < 64; ++r) {
    float acc = 0.f;
    const float* kr = &lk1[r * 32];
    for (int d = 0; d < 32; ++d) acc = fmaf(q[d], kr[d], acc);
    sc[r] = acc;
  }
  {
    unsigned long long used = 0ull;
    for (int it = 0; it < 8; ++it) {
      float best = -INFINITY; int bi = 0;
      for (int r = 0; r < 64; ++r)
        if (!((used >> r) & 1ull) && sc[r] > best) { best = sc[r]; bi = r; }
      used |= 1ull << bi; t1v[it] = best; t1i[it] = bi;
    }
  }
  for (int r = 0; r < 64; ++r) {
    float acc = 0.f;
    const float* kr = &lk2[r * 32];
    for (int d = 0; d < 32; ++d) acc = fmaf(q[d + 32], kr[d], acc);
    sc[r] = acc;
  }
  {
    unsigned long long used = 0ull;
    for (int it = 0; it < 8; ++it) {
      float best = -INFINITY; int bi = 0;
      for (int r = 0; r < 64; ++r)
        if (!((used >> r) & 1ull) && sc[r] > best) { best = sc[r]; bi = r; }
      used |= 1ull << bi; t2v[it] = best; t2i[it] = bi;
    }
  }
  // stage-2 scores: np.einsum = sequential f32 mul+add over d=0..63
  for (int c = 0; c < 64; ++c) {
    const float* r1 = &lk1[t1i[c >> 3] * 32];
    const float* r2 = &lk2[t2i[c & 7] * 32];
    float acc = 0.f;
    for (int d = 0; d < 32; ++d) acc = __fadd_rn(acc, __fmul_rn(q[d], r1[d]));
    for (int d = 0; d < 32; ++d) acc = __fadd_rn(acc, __fmul_rn(q[d + 32], r2[d]));
    sc[c] = acc;
  }
  float cvs[8]; int ccs[8];
  {
    unsigned long long used = 0ull;
    for (int it = 0; it < 8; ++it) {
      float best = -INFINITY; int bi = 0;
      for (int c = 0; c < 64; ++c)
        if (!((used >> c) & 1ull) && sc[c] > best) { best = sc[c]; bi = c; }
      used |= 1ull << bi; cvs[it] = best; ccs[it] = bi;
    }
  }
  // softmax on y = sc*0.125 (exact), numpy-style
  float y[8];
  for (int t = 0; t < 8; ++t) y[t] = cvs[t] * 0.125f;   // exact (pow2)
  float mx = y[0];
  for (int t = 1; t < 8; ++t) if (y[t] > mx) mx = y[t];
  float e[8];
  for (int t = 0; t < 8; ++t)
    e[t] = (float)exp((double)__fsub_rn(y[t], mx));     // fl32(exp64) == expf
  float wsum = __fadd_rn(__fadd_rn(__fadd_rn(e[0], e[1]), __fadd_rn(e[2], e[3])),
                         __fadd_rn(__fadd_rn(e[4], e[5]), __fadd_rn(e[6], e[7])));
  float att[8];
  for (int t = 0; t < 8; ++t) att[t] = __fdiv_rn(e[t], wsum);
  // o = einsum over t: sequential f32 mul+add
  const float* vbh = vb + ((size_t)(kvh * 4096) << 6);
  const float* vr[8];
  for (int t = 0; t < 8; ++t) {
    int cc = ccs[t];
    vr[t] = vbh + ((size_t)(t1i[cc >> 3] * 64 + t2i[cc & 7]) << 6);
  }
  float* op = ob + (size_t)s * 512 + (h << 6);
  for (int d = 0; d < 64; ++d) {
    float acc = 0.f;
    for (int t = 0; t < 8; ++t) acc = __fadd_rn(acc, __fmul_rn(att[t], vr[t][d]));
    op[d] = acc;
  }
}

extern "C" void kernel_launch(void* const* d_in, const int* in_sizes, int n_in,
                              void* d_out, int out_size, void* d_ws, size_t ws_size,
                              hipStream_t stream) {
  const float* x  = (const float*)d_in[0];
  const float* Wq = (const float*)d_in[1];
  const float* Wk = (const float*)d_in[2];
  const float* Wv = (const float*)d_in[3];
  const float* Wo = (const float*)d_in[4];
  float* ws = (float*)d_ws;
  float* qkv  = ws + OFF_QKV;
  float* qb   = ws + OFF_Q;
  float* kb   = ws + OFF_K;
  float* vb   = ws + OFF_V;
  float* cosT = ws + OFF_COS;
  float* sinT = ws + OFF_SIN;
  float* k1t  = ws + OFF_K1;
  float* k2t  = ws + OFF_K2;
  float* ob   = ws + OFF_O;
  float* wcat = ws + OFF_W;

  hipMemcpyAsync(wcat,             Wq, (size_t)512 * 512 * sizeof(float), hipMemcpyDeviceToDevice, stream);
  hipMemcpyAsync(wcat + 512 * 512, Wk, (size_t)256 * 512 * sizeof(float), hipMemcpyDeviceToDevice, stream);
  hipMemcpyAsync(wcat + 768 * 512, Wv, (size_t)256 * 512 * sizeof(float), hipMemcpyDeviceToDevice, stream);

  freq_table_kernel<<<512, 256, 0, stream>>>(cosT, sinT);
  qkv_gemm_np<<<4096, 256, 0, stream>>>(x, wcat, qkv);
  rope_reshape_kernel<<<16384, 256, 0, stream>>>(qkv, cosT, sinT, qb, kb, vb);
  k12_np_kernel<<<64, 256, 0, stream>>>(kb, k1t, k2t);
  attn_np_kernel<<<128, 256, 0, stream>>>(qb, vb, k1t, k2t, ob);
  out_gemm<<<2048, 256, 0, stream>>>(ob, Wo, (float*)d_out);
}

// Round 6
// 315.397 us; speedup vs baseline: 6.0900x; 6.0900x over previous
//
#include <hip/hip_runtime.h>
#include <math.h>

// Problem: S=4096, D=512, H=8, KVH=4, DH=64, M=64, K=8 (B=1)
// ARITHMETIC CONTRACT (frozen, round 5 green): selection-critical path
// emulates numpy-f32 op-for-op:
//  - QKV gemm: per output, sequential f32 fmaf chain in k-ascending order,
//    KC=384 panel split, final __fadd_rn(acc1, acc2)
//  - k1/k2 sums: sequential f32 adds in axis order
//  - stage-2 einsum: sequential f32 mul+add (NOT fma)
//  - tables: correctly-rounded f32 (f64 then round)
//  - softmax: *0.125, fl32(exp64), pairwise-8 sum, f32 div
// This round: LDS-tiled GEMMs preserving the exact chain order (tiles walk
// k ascending => identical fmaf sequence per output).

// Workspace (floats)
static constexpr size_t OFF_QKV = 0;              // 4096*1024
static constexpr size_t OFF_Q   = 4194304;        // 8*4096*64   q[h][s][d]
static constexpr size_t OFF_K   = 6291456;        // 4*4096*64   k[kvh][s][d]
static constexpr size_t OFF_V   = 7340032;        // 4*4096*64   v[kvh][s][d]
static constexpr size_t OFF_COS = 8388608;        // 4096*32
static constexpr size_t OFF_SIN = 8519680;        // 4096*32
static constexpr size_t OFF_K1  = 8650752;        // 4*64*32     k1[kvh][r][d]
static constexpr size_t OFF_K2  = 8658944;        // 4*64*32     k2[kvh][c][d]
static constexpr size_t OFF_O   = 8667136;        // 4096*512
static constexpr size_t OFF_W   = 10764288;       // 1024*512

#define LDT 68  // LDS leading dim pad (64+4)

// f32 tables matching numpy: pf=fl32(10000^(dp/32)); invf=fl32(1/pf);
// argf=fl32(s*invf); cs/sn=fl32(cos/sin_64(argf))
__global__ __launch_bounds__(256) void freq_table_kernel(float* __restrict__ cosT,
    float* __restrict__ sinT) {
  int idx = blockIdx.x * 256 + threadIdx.x;   // 0..131071
  int s = idx >> 5;
  int dp = idx & 31;
  double e = (double)dp * (1.0 / 32.0);
  float pf = (float)pow(10000.0, e);
  float invf = 1.0f / pf;
  float argf = __fmul_rn((float)s, invf);
  cosT[idx] = (float)cos((double)argf);
  sinT[idx] = (float)sin((double)argf);
}

// Tiled NT gemm, chain-order-preserving, KC=384 split.
// C[M][N] = A[M][512] * B[N][512]^T. 64x64 tile, BK=16, 256 thr, 4x4/thread.
// SPLIT != 0: acc1 for k<SPLIT, acc2 for k>=SPLIT, C = fl32(acc1+acc2).
template <int SPLIT>
__global__ __launch_bounds__(256) void gemm_nt_chain(const float* __restrict__ A,
    const float* __restrict__ B, float* __restrict__ C, int N) {
  __shared__ float As[16 * LDT];
  __shared__ float Bs[16 * LDT];
  const int tid = threadIdx.x;
  const int ty = tid >> 4;          // 0..15
  const int tx = tid & 15;          // 0..15
  const int bm = blockIdx.y, bn = blockIdx.x;
  const int lrow = tid >> 2;        // 0..63
  const int lk = (tid & 3) << 2;    // 0,4,8,12
  const float* Ap = A + (size_t)(bm * 64 + lrow) * 512 + lk;
  const float* Bp = B + (size_t)(bn * 64 + lrow) * 512 + lk;
  float acc1[4][4] = {{0.f}};
  float acc2[4][4] = {{0.f}};
  for (int kt = 0; kt < 512; kt += 16) {
    float4 av = *(const float4*)(Ap + kt);
    float4 bv = *(const float4*)(Bp + kt);
    __syncthreads();
    As[(lk + 0) * LDT + lrow] = av.x;
    As[(lk + 1) * LDT + lrow] = av.y;
    As[(lk + 2) * LDT + lrow] = av.z;
    As[(lk + 3) * LDT + lrow] = av.w;
    Bs[(lk + 0) * LDT + lrow] = bv.x;
    Bs[(lk + 1) * LDT + lrow] = bv.y;
    Bs[(lk + 2) * LDT + lrow] = bv.z;
    Bs[(lk + 3) * LDT + lrow] = bv.w;
    __syncthreads();
    if (SPLIT != 0 && kt >= SPLIT) {
      #pragma unroll
      for (int k = 0; k < 16; ++k) {
        float4 a4 = *(const float4*)(&As[k * LDT + (ty << 2)]);
        float4 b4 = *(const float4*)(&Bs[k * LDT + (tx << 2)]);
        float af[4] = {a4.x, a4.y, a4.z, a4.w};
        float bf[4] = {b4.x, b4.y, b4.z, b4.w};
        #pragma unroll
        for (int i2 = 0; i2 < 4; ++i2)
          #pragma unroll
          for (int j2 = 0; j2 < 4; ++j2)
            acc2[i2][j2] = fmaf(af[i2], bf[j2], acc2[i2][j2]);
      }
    } else {
      #pragma unroll
      for (int k = 0; k < 16; ++k) {
        float4 a4 = *(const float4*)(&As[k * LDT + (ty << 2)]);
        float4 b4 = *(const float4*)(&Bs[k * LDT + (tx << 2)]);
        float af[4] = {a4.x, a4.y, a4.z, a4.w};
        float bf[4] = {b4.x, b4.y, b4.z, b4.w};
        #pragma unroll
        for (int i2 = 0; i2 < 4; ++i2)
          #pragma unroll
          for (int j2 = 0; j2 < 4; ++j2)
            acc1[i2][j2] = fmaf(af[i2], bf[j2], acc1[i2][j2]);
      }
    }
  }
  float* Cp = C + (size_t)(bm * 64 + (ty << 2)) * N + bn * 64 + (tx << 2);
  #pragma unroll
  for (int i2 = 0; i2 < 4; ++i2) {
    float4 o4;
    o4.x = __fadd_rn(acc1[i2][0], acc2[i2][0]);
    o4.y = __fadd_rn(acc1[i2][1], acc2[i2][1]);
    o4.z = __fadd_rn(acc1[i2][2], acc2[i2][2]);
    o4.w = __fadd_rn(acc1[i2][3], acc2[i2][3]);
    *(float4*)(Cp + (size_t)i2 * N) = o4;
  }
}

// qkv[s][n] -> rope'd q[h][s][d], k[kvh][s][d]; raw v[kvh][s][d]
__global__ __launch_bounds__(256) void rope_reshape_kernel(const float* __restrict__ raw,
    const float* __restrict__ cosT, const float* __restrict__ sinT,
    float* __restrict__ qb, float* __restrict__ kb, float* __restrict__ vb) {
  int idx = blockIdx.x * 256 + threadIdx.x;
  int s = idx >> 10;
  int n = idx & 1023;
  float val = raw[idx];
  int d = n & 63;
  if (n < 768) {
    int dp = d & 31;
    float cs = cosT[(s << 5) + dp];
    float sn = sinT[(s << 5) + dp];
    int npart = (n - d) + ((d < 32) ? d + 32 : d - 32);
    float partner = raw[(s << 10) + npart];
    float rot = (d < 32) ? -partner : partner;
    float out = __fadd_rn(__fmul_rn(val, cs), __fmul_rn(rot, sn));
    if (n < 512) {
      int h = n >> 6;
      qb[((size_t)(h * 4096 + s) << 6) + d] = out;
    } else {
      int kvh = (n - 512) >> 6;
      kb[((size_t)(kvh * 4096 + s) << 6) + d] = out;
    }
  } else {
    int kvh = (n - 768) >> 6;
    vb[((size_t)(kvh * 4096 + s) << 6) + d] = val;
  }
}

// numpy strided-axis sum: sequential f32 adds in axis order.
// k1[kvh][r][d] = sum_c k[kvh][r*64+c][d]      (d 0..31)
// k2[kvh][c][d] = sum_r k[kvh][r*64+c][d+32]
__global__ __launch_bounds__(256) void k12_np_kernel(const float* __restrict__ kb,
    float* __restrict__ k1t, float* __restrict__ k2t) {
  int id = blockIdx.x * 256 + threadIdx.x;    // 0..16383
  int which = id >> 13;
  int rem = id & 8191;
  int kvh = rem >> 11;
  int rem2 = rem & 2047;
  int i = rem2 >> 5;                          // 0..63
  int d = rem2 & 31;
  const float* base = kb + ((size_t)(kvh * 4096) << 6);
  if (which == 0) {
    float acc = base[((size_t)(i * 64) << 6) + d];
    for (int c = 1; c < 64; ++c)
      acc = __fadd_rn(acc, base[((size_t)(i * 64 + c) << 6) + d]);
    k1t[(kvh * 64 + i) * 32 + d] = acc;
  } else {
    float acc = base[((size_t)i << 6) + d + 32];
    for (int r = 1; r < 64; ++r)
      acc = __fadd_rn(acc, base[((size_t)(r * 64 + i) << 6) + d + 32]);
    k2t[(kvh * 64 + i) * 32 + d] = acc;
  }
}

// One thread per (h,s); all selection arithmetic numpy-f32-faithful.
__global__ __launch_bounds__(256) void attn_np_kernel(const float* __restrict__ qb,
    const float* __restrict__ vb, const float* __restrict__ k1t,
    const float* __restrict__ k2t, float* __restrict__ ob) {
  __shared__ float lk1[2048];   // [r][d] 64x32 for this block's kvh
  __shared__ float lk2[2048];
  int id = blockIdx.x * 256 + threadIdx.x;    // 0..32767
  int h = id >> 12;
  int s = id & 4095;
  int kvh = h >> 1;
  for (int j = threadIdx.x; j < 2048; j += 256) {
    lk1[j] = k1t[kvh * 2048 + j];
    lk2[j] = k2t[kvh * 2048 + j];
  }
  __syncthreads();

  float q[64];
  const float* qp = qb + ((size_t)(h * 4096 + s) << 6);
  for (int d = 0; d < 64; ++d) q[d] = qp[d];

  float sc[64];
  float t1v[8], t2v[8];
  int t1i[8], t2i[8];
  for (int r = 0; r < 64; ++r) {
    float acc = 0.f;
    const float* kr = &lk1[r * 32];
    for (int d = 0; d < 32; ++d) acc = fmaf(q[d], kr[d], acc);
    sc[r] = acc;
  }
  {
    unsigned long long used = 0ull;
    for (int it = 0; it < 8; ++it) {
      float best = -INFINITY; int bi = 0;
      for (int r = 0; r < 64; ++r)
        if (!((used >> r) & 1ull) && sc[r] > best) { best = sc[r]; bi = r; }
      used |= 1ull << bi; t1v[it] = best; t1i[it] = bi;
    }
  }
  for (int r = 0; r < 64; ++r) {
    float acc = 0.f;
    const float* kr = &lk2[r * 32];
    for (int d = 0; d < 32; ++d) acc = fmaf(q[d + 32], kr[d], acc);
    sc[r] = acc;
  }
  {
    unsigned long long used = 0ull;
    for (int it = 0; it < 8; ++it) {
      float best = -INFINITY; int bi = 0;
      for (int r = 0; r < 64; ++r)
        if (!((used >> r) & 1ull) && sc[r] > best) { best = sc[r]; bi = r; }
      used |= 1ull << bi; t2v[it] = best; t2i[it] = bi;
    }
  }
  // stage-2 scores: np.einsum = sequential f32 mul+add over d=0..63
  for (int c = 0; c < 64; ++c) {
    const float* r1 = &lk1[t1i[c >> 3] * 32];
    const float* r2 = &lk2[t2i[c & 7] * 32];
    float acc = 0.f;
    for (int d = 0; d < 32; ++d) acc = __fadd_rn(acc, __fmul_rn(q[d], r1[d]));
    for (int d = 0; d < 32; ++d) acc = __fadd_rn(acc, __fmul_rn(q[d + 32], r2[d]));
    sc[c] = acc;
  }
  float cvs[8]; int ccs[8];
  {
    unsigned long long used = 0ull;
    for (int it = 0; it < 8; ++it) {
      float best = -INFINITY; int bi = 0;
      for (int c = 0; c < 64; ++c)
        if (!((used >> c) & 1ull) && sc[c] > best) { best = sc[c]; bi = c; }
      used |= 1ull << bi; cvs[it] = best; ccs[it] = bi;
    }
  }
  float y[8];
  for (int t = 0; t < 8; ++t) y[t] = cvs[t] * 0.125f;
  float mx = y[0];
  for (int t = 1; t < 8; ++t) if (y[t] > mx) mx = y[t];
  float e[8];
  for (int t = 0; t < 8; ++t)
    e[t] = (float)exp((double)__fsub_rn(y[t], mx));
  float wsum = __fadd_rn(__fadd_rn(__fadd_rn(e[0], e[1]), __fadd_rn(e[2], e[3])),
                         __fadd_rn(__fadd_rn(e[4], e[5]), __fadd_rn(e[6], e[7])));
  float att[8];
  for (int t = 0; t < 8; ++t) att[t] = __fdiv_rn(e[t], wsum);
  const float* vbh = vb + ((size_t)(kvh * 4096) << 6);
  const float* vr[8];
  for (int t = 0; t < 8; ++t) {
    int cc = ccs[t];
    vr[t] = vbh + ((size_t)(t1i[cc >> 3] * 64 + t2i[cc & 7]) << 6);
  }
  float* op = ob + (size_t)s * 512 + (h << 6);
  for (int d = 0; d < 64; ++d) {
    float acc = 0.f;
    for (int t = 0; t < 8; ++t) acc = __fadd_rn(acc, __fmul_rn(att[t], vr[t][d]));
    op[d] = acc;
  }
}

extern "C" void kernel_launch(void* const* d_in, const int* in_sizes, int n_in,
                              void* d_out, int out_size, void* d_ws, size_t ws_size,
                              hipStream_t stream) {
  const float* x  = (const float*)d_in[0];
  const float* Wq = (const float*)d_in[1];
  const float* Wk = (const float*)d_in[2];
  const float* Wv = (const float*)d_in[3];
  const float* Wo = (const float*)d_in[4];
  float* ws = (float*)d_ws;
  float* qkv  = ws + OFF_QKV;
  float* qb   = ws + OFF_Q;
  float* kb   = ws + OFF_K;
  float* vb   = ws + OFF_V;
  float* cosT = ws + OFF_COS;
  float* sinT = ws + OFF_SIN;
  float* k1t  = ws + OFF_K1;
  float* k2t  = ws + OFF_K2;
  float* ob   = ws + OFF_O;
  float* wcat = ws + OFF_W;

  hipMemcpyAsync(wcat,             Wq, (size_t)512 * 512 * sizeof(float), hipMemcpyDeviceToDevice, stream);
  hipMemcpyAsync(wcat + 512 * 512, Wk, (size_t)256 * 512 * sizeof(float), hipMemcpyDeviceToDevice, stream);
  hipMemcpyAsync(wcat + 768 * 512, Wv, (size_t)256 * 512 * sizeof(float), hipMemcpyDeviceToDevice, stream);

  freq_table_kernel<<<512, 256, 0, stream>>>(cosT, sinT);
  // QKV: selection-critical, KC=384 split chain
  gemm_nt_chain<384><<<dim3(1024 / 64, 4096 / 64), 256, 0, stream>>>(x, wcat, qkv, 1024);
  rope_reshape_kernel<<<16384, 256, 0, stream>>>(qkv, cosT, sinT, qb, kb, vb);
  k12_np_kernel<<<64, 256, 0, stream>>>(kb, k1t, k2t);
  attn_np_kernel<<<128, 256, 0, stream>>>(qb, vb, k1t, k2t, ob);
  // Output projection: single chain (SPLIT=0 disables the split path)
  gemm_nt_chain<0><<<dim3(512 / 64, 4096 / 64), 256, 0, stream>>>(ob, Wo, (float*)d_out, 512);
}